// Round 12
// baseline (132.782 us; speedup 1.0000x reference)
//
#include <hip/hip_runtime.h>

#define SDIM 65536
#define BDIM 32
#define RDIM 128
#define NDEG 4
#define NCHUNK 512
#define CHUNK_S 128               /* s-rows per chunk */
#define MTOT (BDIM * SDIM)        /* 2097152 */
#define EPS_BN 1e-5f
#define NSTATB 512                /* k_stats grid */
#define TSLICE (NDEG * BDIM * RDIM)  /* 16384 floats per chunk slice */
#define NGRP 32                   /* reduce stage-A chunk groups */

// ---------------- K1a: per-block partial stats (no atomics, no init needed) ----
__global__ void k_stats(const float* __restrict__ x, float* __restrict__ partial) {
    __shared__ float s_sum[256];
    __shared__ float s_sq[256];
    int tid = threadIdx.x;
    int gid = blockIdx.x * 256 + tid;
    int stride = gridDim.x * 256;
    float sum = 0.f, sq = 0.f;
    const float4* x4 = (const float4*)x;
    for (int i = gid; i < MTOT / 4; i += stride) {
        float4 v = x4[i];
        sum += (v.x + v.y) + (v.z + v.w);
        sq  += (v.x * v.x + v.y * v.y) + (v.z * v.z + v.w * v.w);
    }
    s_sum[tid] = sum; s_sq[tid] = sq;
    __syncthreads();
    for (int off = 128; off > 0; off >>= 1) {
        if (tid < off) { s_sum[tid] += s_sum[tid + off]; s_sq[tid] += s_sq[tid + off]; }
        __syncthreads();
    }
    if (tid == 0) { partial[blockIdx.x * 2] = s_sum[0]; partial[blockIdx.x * 2 + 1] = s_sq[0]; }
}

// ---------------- K1b: finalize stats (1 block) ----------------
__global__ void k_stats_fin(const float* __restrict__ partial, float* __restrict__ stats) {
    __shared__ float s_sum[256];
    __shared__ float s_sq[256];
    int tid = threadIdx.x;
    float sum = partial[tid * 2] + partial[(tid + 256) * 2];
    float sq  = partial[tid * 2 + 1] + partial[(tid + 256) * 2 + 1];
    s_sum[tid] = sum; s_sq[tid] = sq;
    __syncthreads();
    for (int off = 128; off > 0; off >>= 1) {
        if (tid < off) { s_sum[tid] += s_sum[tid + off]; s_sq[tid] += s_sq[tid + off]; }
        __syncthreads();
    }
    if (tid == 0) { stats[0] = s_sum[0]; stats[1] = s_sq[0]; }
}

// ---------------- K2: normalize + transpose -> zT[s][b], LDS tiled ----------------
__global__ void __launch_bounds__(256) k_norm_t(const float* __restrict__ x,
                                                const float* __restrict__ gamma,
                                                const float* __restrict__ bnb,
                                                const float* __restrict__ stats,
                                                float* __restrict__ zT) {
    __shared__ float lds[64][33];   // pad to kill bank conflicts
    int tid = threadIdx.x;
    int s0 = blockIdx.x * 64;
    float mean = stats[0] * (1.f / MTOT);
    float var  = stats[1] * (1.f / MTOT) - mean * mean;
    float istd = rsqrtf(var + EPS_BN);
    float a  = gamma[0] * istd;
    float c0 = bnb[0] - mean * a;

    int sl = tid & 63, bq = tid >> 6;     // load phase: lane along s (coalesced)
#pragma unroll
    for (int k = 0; k < 8; ++k) {
        int b = k * 4 + bq;
        lds[sl][b] = fmaf(a, x[(size_t)b * SDIM + s0 + sl], c0);
    }
    __syncthreads();
    int bl = tid & 31, sq = tid >> 5;     // store phase: lane along b (coalesced)
#pragma unroll
    for (int k = 0; k < 8; ++k) {
        int s = k * 8 + sq;
        zT[(size_t)(s0 + s) * BDIM + bl] = lds[s][bl];
    }
}

// ---------------- K3: outer-product GEMM, u direct-from-global, z-only LDS ----
// Block = (chunk, n), 4 waves = 4 s-planes x 32 contiguous rows.
// Thread tile 8b x 8r: b = 8o..8o+7 (o=lane>>4), r = {4q..4q+3, 64+4q..64+4q+3}.
// Per row: 2 ds_read_b128 (z, 16-lane broadcast, conflict-free) +
//          2 global dwordx4 (wave spans 512B of the U row -> L1-coalesced) +
//          64 FMA. NO barriers in the loop; compiler pipelines freely.
__global__ void __launch_bounds__(256) k_gemm_t(const float* __restrict__ zT,
                                                const float* __restrict__ U,
                                                float* __restrict__ t_part) {
    __shared__ float z_lds[CHUNK_S * BDIM];   // 16 KB = 4096 floats
    int tid = threadIdx.x;
    int pl  = tid >> 6;           // wave = s-plane 0..3
    int ln  = tid & 63;
    int o   = ln >> 4;            // b-octet 0..3
    int q   = ln & 15;            // r-group
    int chunk = blockIdx.x;
    int n     = blockIdx.y;
    size_t s0 = (size_t)chunk * CHUNK_S;

    // stage z chunk (coalesced float4), once
    {
        const float4* src = (const float4*)(zT + s0 * BDIM);
        float4* dst = (float4*)z_lds;
#pragma unroll
        for (int i = 0; i < 4; ++i)
            dst[i * 256 + tid] = src[i * 256 + tid];
    }
    __syncthreads();

    float acc[8][8];
#pragma unroll
    for (int j = 0; j < 8; ++j)
#pragma unroll
        for (int k = 0; k < 8; ++k) acc[j][k] = 0.f;

    const float* zrow = z_lds + (size_t)pl * 32 * BDIM + 8 * o;
    const float* urow = U + (size_t)n * SDIM * RDIM + (s0 + pl * 32) * RDIM + 4 * q;

#pragma unroll 2
    for (int rr = 0; rr < 32; ++rr) {
        float4 za = *(const float4*)(zrow);        // z[s][8o..8o+3]
        float4 zb = *(const float4*)(zrow + 4);    // z[s][8o+4..8o+7]
        float4 ua = *(const float4*)(urow);        // U[s][4q..4q+3]
        float4 ub = *(const float4*)(urow + 64);   // U[s][64+4q..64+4q+3]
        float zv[8] = {za.x, za.y, za.z, za.w, zb.x, zb.y, zb.z, zb.w};
#pragma unroll
        for (int j = 0; j < 8; ++j) {
            acc[j][0] = fmaf(zv[j], ua.x, acc[j][0]);
            acc[j][1] = fmaf(zv[j], ua.y, acc[j][1]);
            acc[j][2] = fmaf(zv[j], ua.z, acc[j][2]);
            acc[j][3] = fmaf(zv[j], ua.w, acc[j][3]);
            acc[j][4] = fmaf(zv[j], ub.x, acc[j][4]);
            acc[j][5] = fmaf(zv[j], ub.y, acc[j][5]);
            acc[j][6] = fmaf(zv[j], ub.z, acc[j][6]);
            acc[j][7] = fmaf(zv[j], ub.w, acc[j][7]);
        }
        zrow += BDIM;
        urow += RDIM;
    }

    // ---- plane combine in z_lds (slot-major: cm[slot*64 + ln], conflict-free) ----
    float* cm = z_lds;
    __syncthreads();                       // everyone done reading z
    if (pl == 1) {
#pragma unroll
        for (int j = 0; j < 8; ++j)
#pragma unroll
            for (int k = 0; k < 8; ++k) cm[(j * 8 + k) * 64 + ln] = acc[j][k];
    }
    __syncthreads();
    if (pl == 0) {
#pragma unroll
        for (int j = 0; j < 8; ++j)
#pragma unroll
            for (int k = 0; k < 8; ++k) acc[j][k] += cm[(j * 8 + k) * 64 + ln];
    }
    __syncthreads();
    if (pl == 2) {
#pragma unroll
        for (int j = 0; j < 8; ++j)
#pragma unroll
            for (int k = 0; k < 8; ++k) cm[(j * 8 + k) * 64 + ln] = acc[j][k];
    }
    __syncthreads();
    if (pl == 0) {
#pragma unroll
        for (int j = 0; j < 8; ++j)
#pragma unroll
            for (int k = 0; k < 8; ++k) acc[j][k] += cm[(j * 8 + k) * 64 + ln];
    }
    __syncthreads();
    if (pl == 3) {
#pragma unroll
        for (int j = 0; j < 8; ++j)
#pragma unroll
            for (int k = 0; k < 8; ++k) cm[(j * 8 + k) * 64 + ln] = acc[j][k];
    }
    __syncthreads();
    if (pl == 0) {
        float* outp = t_part + ((size_t)chunk * NDEG + n) * (BDIM * RDIM);
#pragma unroll
        for (int j = 0; j < 8; ++j) {
#pragma unroll
            for (int k = 0; k < 8; ++k) acc[j][k] += cm[(j * 8 + k) * 64 + ln];
            int b = o * 8 + j;
            *(float4*)(outp + b * RDIM + 4 * q) =
                make_float4(acc[j][0], acc[j][1], acc[j][2], acc[j][3]);
            *(float4*)(outp + b * RDIM + 64 + 4 * q) =
                make_float4(acc[j][4], acc[j][5], acc[j][6], acc[j][7]);
        }
    }
}

// ---------------- K4a: reduce 16-chunk groups, coalesced float4, 512 blocks ----
__global__ void __launch_bounds__(256) k_reduce_a(const float* __restrict__ t_part,
                                                  float* __restrict__ t_mid) {
    int tid = threadIdx.x;
    int strip = blockIdx.x;      // 0..15 (256 float4 each)
    int g     = blockIdx.y;      // 0..31 (16 chunks each)
    int idx4 = strip * 256 + tid;             // 0..4095 within slice
    const float4* tp4 = (const float4*)t_part;
    float4 s = make_float4(0.f, 0.f, 0.f, 0.f);
#pragma unroll
    for (int c = 0; c < 16; ++c) {
        float4 v = tp4[(size_t)(g * 16 + c) * (TSLICE / 4) + idx4];
        s.x += v.x; s.y += v.y; s.z += v.z; s.w += v.w;
    }
    ((float4*)t_mid)[(size_t)g * (TSLICE / 4) + idx4] = s;
}

// ---------------- K4b: final reduce over 32 groups + Horner -> h[b][r] ----------------
__global__ void __launch_bounds__(256) k_reduce_b(const float* __restrict__ t_mid,
                                                  float* __restrict__ h) {
    int i = blockIdx.x * 256 + threadIdx.x;   // 0..4095 = b*128+r
    float t[NDEG];
#pragma unroll
    for (int n = 0; n < NDEG; ++n) t[n] = 0.f;
    for (int g = 0; g < NGRP; ++g) {
#pragma unroll
        for (int n = 0; n < NDEG; ++n)
            t[n] += t_mid[(size_t)g * TSLICE + n * (BDIM * RDIM) + i];
    }
    float hh = t[0];
#pragma unroll
    for (int n = 1; n < NDEG; ++n) hh = fmaf(t[n], hh, hh);
    h[i] = hh;
}

// ---------------- K5: out[b][s] = beta[s] + sum_r h[b][r]*C[s][r], 8-way b-split ----
__global__ void __launch_bounds__(256) k_out(const float* __restrict__ h,
                                             const float* __restrict__ Cm,
                                             const float* __restrict__ beta,
                                             float* __restrict__ out) {
    int tid = threadIdx.x;
    int s   = (blockIdx.x >> 1) * 64 + (tid & 63);
    int bg  = __builtin_amdgcn_readfirstlane((blockIdx.x & 1) * 4 + (tid >> 6));
    int b0  = bg * 4;

    float acc[4] = {0.f, 0.f, 0.f, 0.f};
    const float4* Cr = (const float4*)(Cm + (size_t)s * RDIM);
    const float* hb = h + b0 * RDIM;               // wave-uniform base -> s_load

#pragma unroll 8
    for (int rc = 0; rc < RDIM / 4; ++rc) {
        float4 c = Cr[rc];
#pragma unroll
        for (int j = 0; j < 4; ++j) {
            const float* hr = hb + j * RDIM + rc * 4;
            float a = acc[j];
            a = fmaf(c.x, hr[0], a);
            a = fmaf(c.y, hr[1], a);
            a = fmaf(c.z, hr[2], a);
            a = fmaf(c.w, hr[3], a);
            acc[j] = a;
        }
    }
    float bt = beta[s];
#pragma unroll
    for (int j = 0; j < 4; ++j)
        out[(size_t)(b0 + j) * SDIM + s] = acc[j] + bt;
}

extern "C" void kernel_launch(void* const* d_in, const int* in_sizes, int n_in,
                              void* d_out, int out_size, void* d_ws, size_t ws_size,
                              hipStream_t stream) {
    const float* x     = (const float*)d_in[0];
    const float* U     = (const float*)d_in[1];
    const float* Cm    = (const float*)d_in[2];
    const float* beta  = (const float*)d_in[3];
    const float* gamma = (const float*)d_in[4];
    const float* bnb   = (const float*)d_in[5];
    float* out = (float*)d_out;

    char* ws = (char*)d_ws;
    size_t off = 0;
    float* stats   = (float*)(ws + off); off += 256;
    float* partial = (float*)(ws + off); off += NSTATB * 2 * 4;
    float* zT      = (float*)(ws + off); off += (size_t)BDIM * SDIM * 4;        // 8 MB
    float* t_part  = (float*)(ws + off); off += (size_t)NCHUNK * TSLICE * 4;    // 32 MB
    float* t_mid   = (float*)(ws + off); off += (size_t)NGRP * TSLICE * 4;      // 2 MB
    float* h       = (float*)(ws + off); off += (size_t)BDIM * RDIM * 4;        // 16 KB

    k_stats<<<NSTATB, 256, 0, stream>>>(x, partial);
    k_stats_fin<<<1, 256, 0, stream>>>(partial, stats);
    k_norm_t<<<SDIM / 64, 256, 0, stream>>>(x, gamma, bnb, stats, zT);
    dim3 g3(NCHUNK, NDEG);
    k_gemm_t<<<g3, 256, 0, stream>>>(zT, U, t_part);
    dim3 g4(16, NGRP);
    k_reduce_a<<<g4, 256, 0, stream>>>(t_part, t_mid);
    k_reduce_b<<<16, 256, 0, stream>>>(t_mid, h);
    k_out<<<2048, 256, 0, stream>>>(h, Cm, beta, out);
}